// Round 5
// baseline (339.047 us; speedup 1.0000x reference)
//
#include <hip/hip_runtime.h>
#include <hip/hip_bf16.h>

#define DFEAT 4096
#define NS 128            // K slices of 32

typedef __attribute__((ext_vector_type(8))) short bf16x8;
typedef __attribute__((ext_vector_type(16))) float f32x16;
typedef __attribute__((ext_vector_type(4))) float float4v;

__device__ inline unsigned short f32_to_bf16_rne(float f) {
  union { float f; unsigned u; } v; v.f = f;
  unsigned u = v.u;
  unsigned r = u + 0x7fffu + ((u >> 16) & 1u);
  return (unsigned short)(r >> 16);
}

// Fused prep: blocks [0,4096) build Wt rows; blocks [4096,6144) convert x->bf16.
// Wt[n][k] = psi[k] * sum_r omega[r][n] * g[r][(n-k)&4095]
__global__ void prep_kernel(const float* __restrict__ x,
                            const float* __restrict__ psi,
                            const float* __restrict__ omega,
                            const float* __restrict__ g,
                            unsigned short* __restrict__ Wt,
                            unsigned short* __restrict__ Xb, int n8) {
  int b = blockIdx.x;
  if (b < DFEAT) {
    int n = b;
    float o0 = omega[n];
    float o1 = omega[DFEAT + n];
    float o2 = omega[2 * DFEAT + n];
    const float* g0 = g;
    const float* g1 = g + DFEAT;
    const float* g2 = g + 2 * DFEAT;
    for (int k0 = threadIdx.x * 4; k0 < DFEAT; k0 += blockDim.x * 4) {
      unsigned short res[4];
#pragma unroll
      for (int j = 0; j < 4; ++j) {
        int k = k0 + j;
        int idx = (n - k) & (DFEAT - 1);
        float w = o0 * g0[idx] + o1 * g1[idx] + o2 * g2[idx];
        w *= psi[k];
        res[j] = f32_to_bf16_rne(w);
      }
      uint2 pk;
      pk.x = (unsigned)res[0] | ((unsigned)res[1] << 16);
      pk.y = (unsigned)res[2] | ((unsigned)res[3] << 16);
      *(uint2*)(Wt + (size_t)n * DFEAT + k0) = pk;
    }
  } else {
    int i0 = (b - DFEAT) * blockDim.x + threadIdx.x;
    int stride = (gridDim.x - DFEAT) * blockDim.x;
    for (int i = i0; i < n8; i += stride) {
      size_t base = (size_t)i * 8;
      float4v a = *(const float4v*)(x + base);
      float4v c = *(const float4v*)(x + base + 4);
      union { unsigned short s[8]; uint4 v; } o;
#pragma unroll
      for (int j = 0; j < 4; ++j) o.s[j] = f32_to_bf16_rne(a[j]);
#pragma unroll
      for (int j = 0; j < 4; ++j) o.s[4 + j] = f32_to_bf16_rne(c[j]);
      *(uint4*)(Xb + base) = o.v;
    }
  }
}

// Stage one 256x32 bf16 slice (A or B) of K-slice s into LDS slot, linear dest,
// pre-swizzled (inverse-XOR) global source. 2 x global_load_lds(16B) per thread.
__device__ __forceinline__ void stage(const unsigned short* __restrict__ G,
                                      unsigned short* dstbase,
                                      int baseRow, int s, int t, int wave) {
#pragma unroll
  for (int i = 0; i < 2; ++i) {
    int idx = i * 512 + t;
    int row = idx >> 2;                       // 0..255
    int chunk = (idx & 3) ^ ((row >> 1) & 3); // inverse swizzle on 16B chunks
    const unsigned short* src = G + ((size_t)(baseRow + row) << 12) + (s << 5) + (chunk << 3);
    unsigned short* dst = dstbase + (size_t)(i * 512 + wave * 64) * 8;  // lane-uniform
    __builtin_amdgcn_global_load_lds((const __attribute__((address_space(1))) unsigned int*)src,
                                     (__attribute__((address_space(3))) unsigned int*)dst, 16, 0, 0);
  }
}

// C[M][4096] = A[M][4096] * B[4096][4096]^T + bias; bf16 in, f32 out.
// 256x256 tile, 8 waves, 32x32x16 MFMA fragments, two phases per K-32 slice,
// stages issued right after barriers, counted vmcnt(6), bm-striped XCD swizzle.
__global__ __launch_bounds__(512, 2) void gemm_kernel(
    const unsigned short* __restrict__ A,   // [M][4096] bf16 bits
    const unsigned short* __restrict__ Bm,  // [4096][4096] bf16 bits (Wt)
    const float* __restrict__ bias,
    float* __restrict__ C,
    int M) {
  __shared__ unsigned short lds[4][2][8192];   // [slot][A/B][256*32] = 128 KiB

  const int t = threadIdx.x;
  const int lane = t & 63;
  const int wave = t >> 6;
  const int wm = wave >> 2;    // 0..1
  const int wn = wave & 3;     // 0..3

  int id = blockIdx.x;
  int per = gridDim.x >> 3;                 // blocks per XCD (bijective: grid % 8 == 0)
  int swz = (id & 7) * per + (id >> 3);
  // bm-stripe per XCD: each XCD owns 4 consecutive bm panels, sweeps all 16 bn
  int bm = swz >> 4;           // 0..(M/256-1)
  int bn = swz & 15;           // 0..15
  const int brow = bm << 8;
  const int bcol = bn << 8;

  // 32x32x16 fragment addressing within a 256x32-element LDS slice:
  //   A/B frag: row/col = blk*32 + (lane&31), k = ks*16 + (lane>>5)*8 + e
  //   element offset = row*32 + ((ks*2 + (lane>>5)) ^ ((row>>1)&3)) * 8
  const int laneRow = lane & 31;
  const int xm = (laneRow >> 1) & 3;
  const int ch = lane >> 5;
  const int kOff0 = (((0 * 2 + ch) ^ xm) << 3);
  const int kOff1 = (((1 * 2 + ch) ^ xm) << 3);
  const int baseA = ((wm << 7) + laneRow) * 32;   // + rb*1024 + kOff
  const int baseB = ((wn << 6) + laneRow) * 32;   // + cb*1024 + kOff

  f32x16 acc[4][2] = {};
  // aLo[buf][rb*2+ks] rb in {0,1}; aHi[rb2*2+ks] rb2 in {0,1} -> rows 64..127;
  // bfr[buf][cb*2+ks]
  bf16x8 aLo[2][4], bfr[2][4], aHi[4];

  // prologue: stage slices 0,1,2 (12 gloads, slice-0 pair oldest)
  stage(A,  &lds[0][0][0], brow, 0, t, wave);
  stage(Bm, &lds[0][1][0], bcol, 0, t, wave);
  stage(A,  &lds[1][0][0], brow, 1, t, wave);
  stage(Bm, &lds[1][1][0], bcol, 1, t, wave);
  stage(A,  &lds[2][0][0], brow, 2, t, wave);
  stage(Bm, &lds[2][1][0], bcol, 2, t, wave);
  asm volatile("s_waitcnt vmcnt(8)" ::: "memory");   // slice 0 landed (all waves, pre-barrier)
  __builtin_amdgcn_s_barrier();
  {
    const unsigned short* As0 = &lds[0][0][0];
    const unsigned short* Bs0 = &lds[0][1][0];
#pragma unroll
    for (int rb = 0; rb < 2; ++rb) {
      aLo[0][rb * 2 + 0] = *(const bf16x8*)(As0 + baseA + rb * 1024 + kOff0);
      aLo[0][rb * 2 + 1] = *(const bf16x8*)(As0 + baseA + rb * 1024 + kOff1);
    }
#pragma unroll
    for (int cb = 0; cb < 2; ++cb) {
      bfr[0][cb * 2 + 0] = *(const bf16x8*)(Bs0 + baseB + cb * 1024 + kOff0);
      bfr[0][cb * 2 + 1] = *(const bf16x8*)(Bs0 + baseB + cb * 1024 + kOff1);
    }
  }

  // Phase A: RD aHi(s) | barrier | STAGE A(s+3) | MM0 | vmcnt(VMC)
  // Phase B: barrier | STAGE B(s+3) | RD aLo,b(s+1) | MM1
#define SLICE_BODY(s, CUR, NXT, STA, STB, VMC, DO_RD)                          \
  {                                                                            \
    const unsigned short* As_ = &lds[(s) & 3][0][0];                           \
    _Pragma("unroll")                                                          \
    for (int rb = 0; rb < 2; ++rb) {                                           \
      aHi[rb * 2 + 0] = *(const bf16x8*)(As_ + baseA + (2 + rb) * 1024 + kOff0);\
      aHi[rb * 2 + 1] = *(const bf16x8*)(As_ + baseA + (2 + rb) * 1024 + kOff1);\
    }                                                                          \
    __builtin_amdgcn_s_barrier();                                              \
    if (STA) stage(A, &lds[((s) + 3) & 3][0][0], brow, (s) + 3, t, wave);      \
    __builtin_amdgcn_s_setprio(1);                                             \
    _Pragma("unroll")                                                          \
    for (int rb = 0; rb < 2; ++rb)                                             \
      _Pragma("unroll")                                                        \
      for (int cb = 0; cb < 2; ++cb)                                           \
        _Pragma("unroll")                                                      \
        for (int ks = 0; ks < 2; ++ks)                                         \
          acc[rb][cb] = __builtin_amdgcn_mfma_f32_32x32x16_bf16(               \
              aLo[CUR][rb * 2 + ks], bfr[CUR][cb * 2 + ks], acc[rb][cb], 0, 0, 0);\
    __builtin_amdgcn_s_setprio(0);                                             \
    asm volatile("s_waitcnt vmcnt(" #VMC ")" ::: "memory");                    \
    __builtin_amdgcn_s_barrier();                                              \
    if (STB) stage(Bm, &lds[((s) + 3) & 3][1][0], bcol, (s) + 3, t, wave);     \
    if (DO_RD) {                                                               \
      const unsigned short* An_ = &lds[((s) + 1) & 3][0][0];                   \
      const unsigned short* Bn_ = &lds[((s) + 1) & 3][1][0];                   \
      _Pragma("unroll")                                                        \
      for (int rb = 0; rb < 2; ++rb) {                                         \
        aLo[NXT][rb * 2 + 0] = *(const bf16x8*)(An_ + baseA + rb * 1024 + kOff0);\
        aLo[NXT][rb * 2 + 1] = *(const bf16x8*)(An_ + baseA + rb * 1024 + kOff1);\
      }                                                                        \
      _Pragma("unroll")                                                        \
      for (int cb = 0; cb < 2; ++cb) {                                         \
        bfr[NXT][cb * 2 + 0] = *(const bf16x8*)(Bn_ + baseB + cb * 1024 + kOff0);\
        bfr[NXT][cb * 2 + 1] = *(const bf16x8*)(Bn_ + baseB + cb * 1024 + kOff1);\
      }                                                                        \
    }                                                                          \
    __builtin_amdgcn_s_setprio(1);                                             \
    _Pragma("unroll")                                                          \
    for (int rb = 0; rb < 2; ++rb)                                             \
      _Pragma("unroll")                                                        \
      for (int cb = 0; cb < 2; ++cb)                                           \
        _Pragma("unroll")                                                      \
        for (int ks = 0; ks < 2; ++ks)                                         \
          acc[2 + rb][cb] = __builtin_amdgcn_mfma_f32_32x32x16_bf16(           \
              aHi[rb * 2 + ks], bfr[CUR][cb * 2 + ks], acc[2 + rb][cb], 0, 0, 0);\
    __builtin_amdgcn_s_setprio(0);                                             \
  }

  // main loop: steady-state vmcnt(6) (A/B(s+2) + A(s+3) in flight)
  for (int s = 0; s < NS - 4; s += 2) {
    SLICE_BODY(s,     0, 1, true, true, 6, true);
    SLICE_BODY(s + 1, 1, 0, true, true, 6, true);
  }
  // tail: slices NS-4 .. NS-1
  SLICE_BODY(NS - 4, 0, 1, true,  true,  6, true);   // stages slice NS-1
  SLICE_BODY(NS - 3, 1, 0, false, false, 4, true);
  SLICE_BODY(NS - 2, 0, 1, false, false, 0, true);
  SLICE_BODY(NS - 1, 1, 0, false, false, 0, false);
#undef SLICE_BODY

  // epilogue: 32x32 C/D layout col=lane&31, row=(reg&3)+8*(reg>>2)+4*(lane>>5)
  const int rowOff4 = (lane >> 5) << 2;
#pragma unroll
  for (int rb = 0; rb < 4; ++rb) {
    int rowbase = brow + (wm << 7) + rb * 32 + rowOff4;
#pragma unroll
    for (int cb = 0; cb < 2; ++cb) {
      int col = bcol + (wn << 6) + cb * 32 + laneRow;
      float bv = bias[col];
#pragma unroll
      for (int reg = 0; reg < 16; ++reg) {
        int row = rowbase + (reg & 3) + 8 * (reg >> 2);
        C[((size_t)row << 12) + col] = acc[rb][cb][reg] + bv;
      }
    }
  }
}

extern "C" void kernel_launch(void* const* d_in, const int* in_sizes, int n_in,
                              void* d_out, int out_size, void* d_ws, size_t ws_size,
                              hipStream_t stream) {
  const float* x     = (const float*)d_in[0];
  const float* psi   = (const float*)d_in[1];
  const float* omega = (const float*)d_in[2];
  const float* g     = (const float*)d_in[3];
  const float* bias  = (const float*)d_in[4];

  const int M = in_sizes[0] / DFEAT;   // 8192
  const int N = DFEAT;
  const int K = DFEAT;

  unsigned short* Wt = (unsigned short*)d_ws;                              // 32 MB
  unsigned short* Xb = (unsigned short*)((char*)d_ws + (size_t)N * K * 2); // 64 MB

  int n8 = (M * K) / 8;
  prep_kernel<<<DFEAT + 2048, 256, 0, stream>>>(x, psi, omega, g, Wt, Xb, n8);

  int nwg = (M / 256) * (N / 256);   // 32*16 = 512, divisible by 8
  gemm_kernel<<<nwg, 512, 0, stream>>>(Xb, Wt, bias, (float*)d_out, M);
}

// Round 6
// 279.088 us; speedup vs baseline: 1.2148x; 1.2148x over previous
//
#include <hip/hip_runtime.h>
#include <hip/hip_bf16.h>

#define DFEAT 4096
#define NT 64        // K-tiles of 64
#define NITER 32     // 2 K-tiles per iteration

typedef __attribute__((ext_vector_type(8))) short bf16x8;
typedef __attribute__((ext_vector_type(4))) float f32x4;
typedef __attribute__((ext_vector_type(4))) float float4v;

__device__ inline unsigned short f32_to_bf16_rne(float f) {
  union { float f; unsigned u; } v; v.f = f;
  unsigned u = v.u;
  unsigned r = u + 0x7fffu + ((u >> 16) & 1u);
  return (unsigned short)(r >> 16);
}

// Wt[n][k] = psi[k] * sum_r omega[r][n] * g[r][(n-k)&4095], bf16, row-major [4096][4096]
__global__ void build_wt_kernel(const float* __restrict__ psi,
                                const float* __restrict__ omega,
                                const float* __restrict__ g,
                                unsigned short* __restrict__ Wt) {
  int n = blockIdx.x;
  float o0 = omega[n];
  float o1 = omega[DFEAT + n];
  float o2 = omega[2 * DFEAT + n];
  const float* g0 = g;
  const float* g1 = g + DFEAT;
  const float* g2 = g + 2 * DFEAT;
  for (int k = threadIdx.x; k < DFEAT; k += blockDim.x) {
    int idx = (n - k) & (DFEAT - 1);
    float w = o0 * g0[idx] + o1 * g1[idx] + o2 * g2[idx];
    w *= psi[k];
    Wt[(size_t)n * DFEAT + k] = f32_to_bf16_rne(w);
  }
}

// x (f32) -> bf16 bits, 8 elements/thread
__global__ void convert_x_kernel(const float* __restrict__ x,
                                 unsigned short* __restrict__ Xb, int n8) {
  int stride = gridDim.x * blockDim.x;
  for (int i = blockIdx.x * blockDim.x + threadIdx.x; i < n8; i += stride) {
    size_t base = (size_t)i * 8;
    float4v a = *(const float4v*)(x + base);
    float4v b = *(const float4v*)(x + base + 4);
    union { unsigned short s[8]; uint4 v; } o;
#pragma unroll
    for (int j = 0; j < 4; ++j) o.s[j] = f32_to_bf16_rne(a[j]);
#pragma unroll
    for (int j = 0; j < 4; ++j) o.s[4 + j] = f32_to_bf16_rne(b[j]);
    *(uint4*)(Xb + base) = o.v;
  }
}

// Stage one 128x64 bf16 half-tile into LDS (linear dest, inverse-swizzled global
// source chunk: c_src = chunk' ^ (row&7)). 2 x global_load_lds(16B) per thread.
__device__ __forceinline__ void stageHalf(const unsigned short* __restrict__ G,
                                          int rowBase,            // brow/bcol + h*128
                                          unsigned short* halfBase,
                                          int tile, int srow, int sc, int wave) {
#pragma unroll
  for (int i = 0; i < 2; ++i) {
    const unsigned short* src =
        G + ((size_t)(rowBase + i * 64 + srow) << 12) + (tile << 6) + (sc << 3);
    unsigned short* dst = halfBase + i * 4096 + wave * 512;   // lane-uniform base
    __builtin_amdgcn_global_load_lds((const __attribute__((address_space(1))) unsigned int*)src,
                                     (__attribute__((address_space(3))) unsigned int*)dst, 16, 0, 0);
  }
}

// C[M][4096] = A[M][4096] * B[4096][4096]^T + bias; bf16 in, f32 out.
// m201-style 8-phase schedule: 256x256 tile, BK=64, 8 waves (2Mx4N),
// 2 K-tiles/iter, 16 MFMA + half-tile stage per phase, vmcnt(4) at ph3/ph7.
__global__ __launch_bounds__(512, 2) void gemm_kernel(
    const unsigned short* __restrict__ A,   // [M][4096] bf16 bits
    const unsigned short* __restrict__ Bm,  // [4096][4096] bf16 bits (Wt)
    const float* __restrict__ bias,
    float* __restrict__ C,
    int M) {
  // [buf][op A=0/B=1][half][128*64 elements] = 128 KiB
  __shared__ unsigned short L[2][2][2][8192];

  const int t = threadIdx.x;
  const int lane = t & 63;
  const int wave = t >> 6;
  const int wm = wave >> 2;    // 0..1  (A-half = wm)
  const int wn = wave & 3;     // 0..3  (B-half = wn>>1)

  int id = blockIdx.x;
  int per = gridDim.x >> 3;               // bijective: grid % 8 == 0
  int swz = (id & 7) * per + (id >> 3);
  int bm = swz >> 4;                      // bm-stripe per XCD (L2/L3 locality, R4-proven)
  int bn = swz & 15;
  const int brow = bm << 8;
  const int bcol = bn << 8;

  // fragment addressing: element offset within a [128][64] half =
  //   row*64 + ((ks*4 + chunk) ^ (row&7)) * 8 ; row&7 == lane&7 for all frags
  const int r15 = lane & 15;
  const int ch = (lane >> 4) & 3;
  const int x7 = lane & 7;
  const int ko0 = ((ch ^ x7) << 3);         // ks=0
  const int ko1 = (((4 + ch) ^ x7) << 3);   // ks=1
  const int bRow = (wn & 1) * 64;
  // staging per-thread constants
  const int srow = t >> 3;                  // 0..63 per call-half
  const int sc = (t & 7) ^ (srow & 7);      // inverse-swizzled source chunk

  const unsigned short* A0h = &L[0][0][wm][0];
  const unsigned short* B0h = &L[0][1][wn >> 1][0];
  const unsigned short* A1h = &L[1][0][wm][0];
  const unsigned short* B1h = &L[1][1][wn >> 1][0];

  f32x4 acc[8][4] = {};
  bf16x8 a[2][2], b[4][2];

#define RD_A(Hp, q) do {                                                      \
    a[0][0] = *(const bf16x8*)((Hp) + ((q) * 32 + 0 + r15) * 64 + ko0);       \
    a[0][1] = *(const bf16x8*)((Hp) + ((q) * 32 + 0 + r15) * 64 + ko1);       \
    a[1][0] = *(const bf16x8*)((Hp) + ((q) * 32 + 16 + r15) * 64 + ko0);      \
    a[1][1] = *(const bf16x8*)((Hp) + ((q) * 32 + 16 + r15) * 64 + ko1);      \
  } while (0)

#define RD_B(Hp) do {                                                         \
    _Pragma("unroll")                                                         \
    for (int j = 0; j < 4; ++j) {                                             \
      b[j][0] = *(const bf16x8*)((Hp) + (bRow + j * 16 + r15) * 64 + ko0);    \
      b[j][1] = *(const bf16x8*)((Hp) + (bRow + j * 16 + r15) * 64 + ko1);    \
    }                                                                         \
  } while (0)

#define MM(q) do {                                                            \
    __builtin_amdgcn_s_setprio(1);                                            \
    _Pragma("unroll")                                                         \
    for (int j = 0; j < 4; ++j) {                                             \
      acc[2*(q)][j]   = __builtin_amdgcn_mfma_f32_16x16x32_bf16(a[0][0], b[j][0], acc[2*(q)][j],   0, 0, 0); \
      acc[2*(q)][j]   = __builtin_amdgcn_mfma_f32_16x16x32_bf16(a[0][1], b[j][1], acc[2*(q)][j],   0, 0, 0); \
      acc[2*(q)+1][j] = __builtin_amdgcn_mfma_f32_16x16x32_bf16(a[1][0], b[j][0], acc[2*(q)+1][j], 0, 0, 0); \
      acc[2*(q)+1][j] = __builtin_amdgcn_mfma_f32_16x16x32_bf16(a[1][1], b[j][1], acc[2*(q)+1][j], 0, 0, 0); \
    }                                                                         \
    __builtin_amdgcn_s_setprio(0);                                            \
  } while (0)

#define BAR do { __builtin_amdgcn_s_barrier(); asm volatile("" ::: "memory"); } while (0)

  // prologue: B(0), A(0), B(1) staged (12 gloads); wait all but B(1)
  stageHalf(Bm, bcol + 0,   &L[0][1][0][0], 0, srow, sc, wave);
  stageHalf(Bm, bcol + 128, &L[0][1][1][0], 0, srow, sc, wave);
  stageHalf(A,  brow + 0,   &L[0][0][0][0], 0, srow, sc, wave);
  stageHalf(A,  brow + 128, &L[0][0][1][0], 0, srow, sc, wave);
  stageHalf(Bm, bcol + 0,   &L[1][1][0][0], 1, srow, sc, wave);
  stageHalf(Bm, bcol + 128, &L[1][1][1][0], 1, srow, sc, wave);
  asm volatile("s_waitcnt vmcnt(4)" ::: "memory");
  BAR;

  for (int it = 0; it < NITER - 1; ++it) {
    const int s = 2 * it;
    // ph0: tile s quadrant 0 (+ all B(s) frags); stage Ah0(s+1)
    RD_B(B0h); RD_A(A0h, 0);
    stageHalf(A, brow + 0,    &L[1][0][0][0], s + 1, srow, sc, wave);
    BAR; MM(0); BAR;
    // ph1
    RD_A(A0h, 1);
    stageHalf(A, brow + 128,  &L[1][0][1][0], s + 1, srow, sc, wave);
    BAR; MM(1); BAR;
    // ph2
    RD_A(A0h, 2);
    stageHalf(Bm, bcol + 0,   &L[0][1][0][0], s + 2, srow, sc, wave);
    BAR; MM(2); BAR;
    // ph3: checkpoint — A(s+1), B(s+1) landed; leave B(s+2) in flight
    RD_A(A0h, 3);
    stageHalf(Bm, bcol + 128, &L[0][1][1][0], s + 2, srow, sc, wave);
    BAR; MM(3);
    asm volatile("s_waitcnt vmcnt(4)" ::: "memory");
    BAR;
    // ph4: tile s+1 quadrant 0
    RD_B(B1h); RD_A(A1h, 0);
    stageHalf(A, brow + 0,    &L[0][0][0][0], s + 2, srow, sc, wave);
    BAR; MM(0); BAR;
    // ph5
    RD_A(A1h, 1);
    stageHalf(A, brow + 128,  &L[0][0][1][0], s + 2, srow, sc, wave);
    BAR; MM(1); BAR;
    // ph6
    RD_A(A1h, 2);
    stageHalf(Bm, bcol + 0,   &L[1][1][0][0], s + 3, srow, sc, wave);
    BAR; MM(2); BAR;
    // ph7: checkpoint — A(s+2), B(s+2) landed; leave B(s+3) in flight
    RD_A(A1h, 3);
    stageHalf(Bm, bcol + 128, &L[1][1][1][0], s + 3, srow, sc, wave);
    BAR; MM(3);
    asm volatile("s_waitcnt vmcnt(4)" ::: "memory");
    BAR;
  }

  // peeled last iteration (tiles NT-2, NT-1): only A(NT-1) still to stage
  RD_B(B0h); RD_A(A0h, 0);
  stageHalf(A, brow + 0,   &L[1][0][0][0], NT - 1, srow, sc, wave);
  BAR; MM(0); BAR;
  RD_A(A0h, 1);
  stageHalf(A, brow + 128, &L[1][0][1][0], NT - 1, srow, sc, wave);
  BAR; MM(1); BAR;
  RD_A(A0h, 2); BAR; MM(2); BAR;
  RD_A(A0h, 3); BAR; MM(3);
  asm volatile("s_waitcnt vmcnt(0)" ::: "memory");
  BAR;
  RD_B(B1h); RD_A(A1h, 0); BAR; MM(0); BAR;
  RD_A(A1h, 1); BAR; MM(1); BAR;
  RD_A(A1h, 2); BAR; MM(2); BAR;
  RD_A(A1h, 3); BAR; MM(3);

#undef RD_A
#undef RD_B
#undef MM
#undef BAR

  // epilogue: 16x16 C/D layout col=lane&15, row=(lane>>4)*4+reg
  const int cr = (lane >> 4) << 2;
#pragma unroll
  for (int fr = 0; fr < 8; ++fr) {
    int row = brow + (wm << 7) + fr * 16 + cr;
#pragma unroll
    for (int fc = 0; fc < 4; ++fc) {
      int col = bcol + (wn << 6) + fc * 16 + r15;
      float bv = bias[col];
      float* cp = C + ((size_t)row << 12) + col;
#pragma unroll
      for (int r = 0; r < 4; ++r)
        cp[(size_t)r << 12] = acc[fr][fc][r] + bv;
    }
  }
}

extern "C" void kernel_launch(void* const* d_in, const int* in_sizes, int n_in,
                              void* d_out, int out_size, void* d_ws, size_t ws_size,
                              hipStream_t stream) {
  const float* x     = (const float*)d_in[0];
  const float* psi   = (const float*)d_in[1];
  const float* omega = (const float*)d_in[2];
  const float* g     = (const float*)d_in[3];
  const float* bias  = (const float*)d_in[4];

  const int M = in_sizes[0] / DFEAT;   // 8192
  const int N = DFEAT;
  const int K = DFEAT;

  unsigned short* Wt = (unsigned short*)d_ws;                              // 32 MB
  unsigned short* Xb = (unsigned short*)((char*)d_ws + (size_t)N * K * 2); // 64 MB

  build_wt_kernel<<<DFEAT, 256, 0, stream>>>(psi, omega, g, Wt);

  int n8 = (M * K) / 8;
  convert_x_kernel<<<2048, 256, 0, stream>>>(x, Xb, n8);

  int nwg = (M / 256) * (N / 256);   // 32*16 = 512, divisible by 8
  gemm_kernel<<<nwg, 512, 0, stream>>>(Xb, Wt, bias, (float*)d_out, M);
}